// Round 7
// baseline (202.520 us; speedup 1.0000x reference)
//
#include <hip/hip_runtime.h>
#include <stdint.h>

typedef unsigned short u16;
typedef __attribute__((ext_vector_type(8))) short bf16x8;   // 8 bf16 in 4 VGPR
typedef __attribute__((ext_vector_type(4))) float f32x4;

#define NSEQ  2048
#define EMBED 1024
#define NHEAD 16
#define HDIM  64
// 1/sqrt(HDIM) * log2(e): S is computed in log2 domain so P = exp2(S - m)
#define QSCALE 0.1803368801111204f

// fp32 -> bf16, round-nearest-even
__device__ __forceinline__ u16 f2bf(float f) {
  uint32_t u = __builtin_bit_cast(uint32_t, f);
  u += 0x7fffu + ((u >> 16) & 1u);
  return (u16)(u >> 16);
}

// pack two fp32 -> two bf16 (RNE) in one u32 (low = a): single VALU instr
__device__ __forceinline__ uint32_t cvtpk(float a, float b) {
  uint32_t r;
  asm("v_cvt_pk_bf16_f32 %0, %1, %2" : "=v"(r) : "v"(a), "v"(b));
  return r;
}

// raw v_exp_f32 (2^x), 1 instr; arg <= 0 here, large-negative underflows to 0
__device__ __forceinline__ float ex2f(float x) {
  float r;
  asm("v_exp_f32 %0, %1" : "=v"(r) : "v"(x));
  return r;
}

// async global->LDS, 16B per lane. Dest must be wave-uniform base (+lane*16 implied).
__device__ __forceinline__ void gl_lds16(const void* g, void* l) {
  __builtin_amdgcn_global_load_lds(
      (const __attribute__((address_space(1))) void*)g,
      (__attribute__((address_space(3))) void*)l, 16, 0, 0);
}

// ---------------------------------------------------------------------------
// fp32 -> bf16 weight conversion (w_qkv: 3072x1024, w_out: 1024x1024)
// ---------------------------------------------------------------------------
struct alignas(8) us4 { u16 a, b, c, d; };

__global__ __launch_bounds__(256)
void convertw(const float* __restrict__ wq, const float* __restrict__ wo,
              u16* __restrict__ oq, u16* __restrict__ oo) {
  int idx = blockIdx.x * 256 + threadIdx.x;          // one float4 per thread
  const float* src;
  u16* dst;
  if (idx < 786432) { src = wq; dst = oq; }          // 3072*1024/4
  else { idx -= 786432; src = wo; dst = oo; }        // 1024*1024/4
  f32x4 v = ((const f32x4*)src)[idx];
  us4 r;
  r.a = f2bf(v[0]); r.b = f2bf(v[1]); r.c = f2bf(v[2]); r.d = f2bf(v[3]);
  ((us4*)dst)[idx] = r;
}

// ---------------------------------------------------------------------------
// x [B][C][N] fp32 -> xT [B][N][C] bf16   (LDS 32x33 tile transpose)
// ---------------------------------------------------------------------------
__global__ __launch_bounds__(256)
void transpose_x(const float* __restrict__ x, u16* __restrict__ xT) {
  __shared__ float tile[32][33];
  const int b = blockIdx.z;
  const int n0 = blockIdx.x * 32, c0 = blockIdx.y * 32;
  const int tx = threadIdx.x & 31, ty = threadIdx.x >> 5;   // ty 0..7
  const float* xb = x + (size_t)b * EMBED * NSEQ;
  #pragma unroll
  for (int k = 0; k < 4; ++k)
    tile[ty + k * 8][tx] = xb[(size_t)(c0 + ty + k * 8) * NSEQ + n0 + tx];
  __syncthreads();
  u16* xTb = xT + (size_t)b * NSEQ * EMBED;
  #pragma unroll
  for (int k = 0; k < 4; ++k)
    xTb[(size_t)(n0 + ty + k * 8) * EMBED + c0 + tx] = f2bf(tile[tx][ty + k * 8]);
}

// ---------------------------------------------------------------------------
// Generic C = A * B^T GEMM, A:[M][1024] bf16, B:[NC][1024] bf16, K=1024.
// Tile (MR*32) x 128, BK=64, 4 waves, 16x16x32 bf16 MFMA, fp32 acc.
// DOUBLE-BUFFERED LDS, statically unrolled 2-phase prefetch: stage tile t+1
// into the other buffer, compute tile t, ONE barrier per K-step (its vmcnt
// drain completes the prefetch). Pointer-increment global addressing.
// XCD-bijective swizzle of the (m,n) tile id for B-panel L2 reuse.
// EPI 0 (MR=4): qkv projection (scatter Q(pre-scaled), K, Vt)
// EPI 1 (MR=2): output projection (store fp32 y)
// ---------------------------------------------------------------------------
template<int EPI, int MR>
__global__ __launch_bounds__(256, 2)
void gemm_bt(const u16* __restrict__ A, const u16* __restrict__ Bm,
             u16* __restrict__ o_q, u16* __restrict__ o_k, u16* __restrict__ o_vt,
             float* __restrict__ o_f)
{
  __shared__ u16 lA[2][MR * 32 * 64];
  __shared__ u16 lB[2][128 * 64];
  const int t  = threadIdx.x;
  const int w  = t >> 6;
  const int l  = t & 63;
  const int lr = l & 15, lh = l >> 4;
  const int wm = w >> 1, wn = w & 1;
  const int bz = blockIdx.z;
  // XCD-bijective remap: NT tiles/batch, NT%8==0
  const int NT  = (EPI == 0 ? 384 : 256);
  const int c   = blockIdx.x + 16 * blockIdx.y;
  const int swz = (c & 7) * (NT / 8) + (c >> 3);
  const int m0  = (swz & 15) * (MR * 32);
  const int n0  = (swz >> 4) * 128;

  const u16* Ab = A  + (EPI == 0 ? (size_t)bz * NSEQ * EMBED : (size_t)0);
  const u16* Bb = Bm + (EPI == 0 ? (size_t)0 : (size_t)bz * NSEQ * EMBED);

  f32x4 acc[MR][4];
  #pragma unroll
  for (int i = 0; i < MR; ++i)
    #pragma unroll
    for (int j = 0; j < 4; ++j)
      acc[i][j] = (f32x4){0.f, 0.f, 0.f, 0.f};

  const int srow = t >> 3;      // 0..31 within an issue
  const int slot = t & 7;       // 16B slot within 128B row
  const int sc   = ((slot * 16) ^ ((srow & 7) << 4)) >> 1;  // swizzled col (elems)
  const u16* aP = Ab + (size_t)(m0 + srow) * EMBED + sc;    // advances +128/iter
  const u16* bP = Bb + (size_t)(n0 + srow) * EMBED + sc;
  char* const ldsAd = (char*)nullptr;  // silence unused in some branches

// stage one BK=64 K-slab at elem offset KOFF into buffers LA_/LB_
#define GSTAGE(KOFF, LA_, LB_) do {                                            \
    _Pragma("unroll")                                                          \
    for (int i_ = 0; i_ < MR; ++i_)                                            \
      gl_lds16(aP + (KOFF) + (size_t)i_ * 32 * EMBED,                          \
               (char*)(LA_) + i_ * 4096 + (w << 10));                          \
    _Pragma("unroll")                                                          \
    for (int i_ = 0; i_ < 4; ++i_)                                             \
      gl_lds16(bP + (KOFF) + (size_t)i_ * 32 * EMBED,                          \
               (char*)(LB_) + i_ * 4096 + (w << 10));                          \
  } while (0)

// compute one BK=64 K-slab from buffers LA_/LB_
#define GCOMP(LA_, LB_) do {                                                   \
    _Pragma("unroll")                                                          \
    for (int kk_ = 0; kk_ < 2; ++kk_) {                                        \
      bf16x8 af_[MR], bf_[4];                                                  \
      _Pragma("unroll")                                                        \
      for (int mr_ = 0; mr_ < MR; ++mr_) {                                     \
        const int row_ = wm * (MR * 16) + mr_ * 16 + lr;                       \
        const int c2_  = (kk_ * 64 + lh * 16) ^ ((row_ & 7) << 4);             \
        af_[mr_] = *(const bf16x8*)((const char*)(LA_) + row_ * 128 + c2_);    \
      }                                                                        \
      _Pragma("unroll")                                                        \
      for (int nc_ = 0; nc_ < 4; ++nc_) {                                      \
        const int row_ = wn * 64 + nc_ * 16 + lr;                              \
        const int c2_  = (kk_ * 64 + lh * 16) ^ ((row_ & 7) << 4);             \
        bf_[nc_] = *(const bf16x8*)((const char*)(LB_) + row_ * 128 + c2_);    \
      }                                                                        \
      _Pragma("unroll")                                                        \
      for (int mr_ = 0; mr_ < MR; ++mr_)                                       \
        _Pragma("unroll")                                                      \
        for (int nc_ = 0; nc_ < 4; ++nc_)                                      \
          acc[mr_][nc_] = __builtin_amdgcn_mfma_f32_16x16x32_bf16(             \
              af_[mr_], bf_[nc_], acc[mr_][nc_], 0, 0, 0);                     \
    }                                                                          \
  } while (0)

  (void)ldsAd;
  // prologue: stage tile 0 -> buf0
  GSTAGE(0, lA[0], lB[0]);
  __syncthreads();
  // main: 7 x 2 tiles; stage-next-before-compute, one barrier per tile
  for (int tt = 0; tt < 7; ++tt) {
    GSTAGE(64, lA[1], lB[1]);
    GCOMP(lA[0], lB[0]);
    __syncthreads();
    GSTAGE(128, lA[0], lB[0]);
    GCOMP(lA[1], lB[1]);
    __syncthreads();
    aP += 128; bP += 128;
  }
  // tail: tiles 14 (buf0, staged) and 15
  GSTAGE(64, lA[1], lB[1]);
  GCOMP(lA[0], lB[0]);
  __syncthreads();
  GCOMP(lA[1], lB[1]);
#undef GSTAGE
#undef GCOMP

  if constexpr (EPI == 0) {
    // rows = n (sequence), cols = o in [0,3072): o = h*192 + {q|k|v}*64 + d
    #pragma unroll
    for (int mr = 0; mr < MR; ++mr) {
      #pragma unroll
      for (int nc = 0; nc < 4; ++nc) {
        const int o  = n0 + wn * 64 + nc * 16 + lr;
        const int h  = o / 192;
        const int rr = o - h * 192;
        const size_t bh = (size_t)bz * NHEAD + h;
        #pragma unroll
        for (int r = 0; r < 4; ++r) {
          const int n = m0 + wm * (MR * 16) + mr * 16 + lh * 4 + r;
          if (rr < 64)       o_q [(bh * NSEQ + n) * HDIM + rr]         = f2bf(acc[mr][nc][r] * QSCALE);
          else if (rr < 128) o_k [(bh * NSEQ + n) * HDIM + (rr - 64)]  = f2bf(acc[mr][nc][r]);
          else               o_vt[(bh * HDIM + (rr - 128)) * NSEQ + n] = f2bf(acc[mr][nc][r]);
        }
      }
    }
  } else {
    // rows = o (out channel), cols = n; y[b][o][n] fp32, coalesced over n
    #pragma unroll
    for (int mr = 0; mr < MR; ++mr)
      #pragma unroll
      for (int nc = 0; nc < 4; ++nc)
        #pragma unroll
        for (int r = 0; r < 4; ++r) {
          const int o = m0 + wm * (MR * 16) + mr * 16 + lh * 4 + r;
          const int n = n0 + wn * 64 + nc * 16 + lr;
          o_f[((size_t)bz * EMBED + o) * NSEQ + n] = acc[mr][nc][r];
        }
  }
}

// ---------------------------------------------------------------------------
// Flash attention v5: swapped operands (lane-diagonal softmax), static 2x
// unrolled K/V dbuf, pointer-increment staging, raw v_exp_f32, wave-uniform
// defer-max (__any), per-lane partial lsum, XCD-aware bh placement, cvt_pk.
// LDS 40 KB -> 4 blocks/CU; grid 1024 = 4 blocks/CU exactly.
// ---------------------------------------------------------------------------
__global__ __launch_bounds__(256, 4)
void attn(const u16* __restrict__ Q, const u16* __restrict__ K,
          const u16* __restrict__ Vt, u16* __restrict__ vals)
{
  __shared__ u16 lK[2][64 * 64], lV[2][64 * 64], lQP[64 * 64];
  const int t  = threadIdx.x;
  const int w  = t >> 6, l = t & 63;
  const int lr = l & 15, lh = l >> 4;
  // XCD-aware decode: xcd = bid&7 owns bh { xcd, xcd+8, xcd+16, xcd+24 }
  const int bid = blockIdx.x;
  const int s   = bid >> 3;                  // 0..127
  const int bh  = (bid & 7) + 8 * (s >> 5);  // 4 whole heads per XCD
  const int q0  = (s & 31) * 64;
  const int b  = bh >> 4, h = bh & 15;
  const size_t qk0 = (size_t)bh * NSEQ * HDIM;
  const size_t vt0 = (size_t)bh * HDIM * NSEQ;
  const int srow = t >> 3, slot = t & 7;
  const int sc   = ((slot * 16) ^ ((srow & 7) << 4)) >> 1;  // staging col (elems)
  const int swzr = (lr & 7) << 4;
  char* const pbase = (char*)lQP + (w << 11) + lr * 128;  // wave-private P row

  // running global pointers (advance by 128 keys per outer iter)
  const u16* kP = K  + qk0 + (size_t)srow * HDIM + sc;
  const u16* vP = Vt + vt0 + (size_t)srow * NSEQ + sc;

// stage one 64-key K/V tile: key offset = KOFF elems into kP / VOFF into vP
#define STAGE(KOFF, VOFF, KB, VB) do {                                         \
    _Pragma("unroll")                                                          \
    for (int i_ = 0; i_ < 2; ++i_) {                                           \
      gl_lds16(kP + (KOFF) + (size_t)i_ * 32 * HDIM,                           \
               (char*)(KB) + i_ * 4096 + (w << 10));                           \
      gl_lds16(vP + (VOFF) + (size_t)i_ * 32 * NSEQ,                           \
               (char*)(VB) + i_ * 4096 + (w << 10));                           \
    }                                                                          \
  } while (0)

// process one 64-key tile from buffers KB/VB (S^T -> softmax -> O^T += PV)
#define ATILE(KB, VB) do {                                                     \
    f32x4 accS[4];                                                             \
    _Pragma("unroll")                                                          \
    for (int f_ = 0; f_ < 4; ++f_) accS[f_] = (f32x4){0.f, 0.f, 0.f, 0.f};     \
    __builtin_amdgcn_s_setprio(1);                                             \
    _Pragma("unroll")                                                          \
    for (int kk_ = 0; kk_ < 2; ++kk_)                                          \
      _Pragma("unroll")                                                        \
      for (int f_ = 0; f_ < 4; ++f_) {                                         \
        const int row_ = f_ * 16 + lr;                                         \
        const int c2_  = (kk_ * 64 + lh * 16) ^ swzr;                          \
        bf16x8 kf_ = *(const bf16x8*)((const char*)(KB) + row_ * 128 + c2_);   \
        accS[f_] = __builtin_amdgcn_mfma_f32_16x16x32_bf16(kf_, qf[kk_],       \
                                                           accS[f_], 0, 0, 0);\
      }                                                                        \
    __builtin_amdgcn_s_setprio(0);                                             \
    float fm0_ = fmaxf(fmaxf(accS[0][0], accS[0][1]), fmaxf(accS[0][2], accS[0][3])); \
    float fm1_ = fmaxf(fmaxf(accS[1][0], accS[1][1]), fmaxf(accS[1][2], accS[1][3])); \
    float fm2_ = fmaxf(fmaxf(accS[2][0], accS[2][1]), fmaxf(accS[2][2], accS[2][3])); \
    float fm3_ = fmaxf(fmaxf(accS[3][0], accS[3][1]), fmaxf(accS[3][2], accS[3][3])); \
    float tm_ = fmaxf(fmaxf(fm0_, fm1_), fmaxf(fm2_, fm3_));                   \
    tm_ = fmaxf(tm_, __shfl_xor(tm_, 16, 64));                                 \
    tm_ = fmaxf(tm_, __shfl_xor(tm_, 32, 64));                                 \
    if (__any(tm_ - m > 8.f)) {   /* wave-uniform defer-max */                 \
      const float nm_ = fmaxf(m, tm_);                                         \
      const float al_ = ex2f(m - nm_);   /* lanes w/o growth: ex2(0)=1 */      \
      lsum *= al_;                                                             \
      _Pragma("unroll")                                                        \
      for (int fd_ = 0; fd_ < 4; ++fd_)                                        \
        _Pragma("unroll")                                                      \
        for (int r_ = 0; r_ < 4; ++r_) accO[fd_][r_] *= al_;                   \
      m = nm_;                                                                 \
    }                                                                          \
    _Pragma("unroll")                                                          \
    for (int f_ = 0; f_ < 4; ++f_) {                                           \
      const float e0_ = ex2f(accS[f_][0] - m);                                 \
      const float e1_ = ex2f(accS[f_][1] - m);                                 \
      const float e2_ = ex2f(accS[f_][2] - m);                                 \
      const float e3_ = ex2f(accS[f_][3] - m);                                 \
      lsum += (e0_ + e1_) + (e2_ + e3_);   /* per-lane partial */              \
      uint2 pw_;                                                               \
      pw_.x = cvtpk(e0_, e1_);                                                 \
      pw_.y = cvtpk(e2_, e3_);                                                 \
      *(uint2*)(pbase + ((f_ * 32 + lh * 8) ^ swzr)) = pw_;                    \
    }                                                                          \
    __builtin_amdgcn_s_setprio(1);                                             \
    _Pragma("unroll")                                                          \
    for (int kk_ = 0; kk_ < 2; ++kk_) {                                        \
      bf16x8 pf_ = *(const bf16x8*)(pbase + ((kk_ * 64 + lh * 16) ^ swzr));    \
      _Pragma("unroll")                                                        \
      for (int fd_ = 0; fd_ < 4; ++fd_) {                                      \
        const int row_ = fd_ * 16 + lr;                                        \
        const int c2_  = (kk_ * 64 + lh * 16) ^ swzr;                          \
        bf16x8 vf_ = *(const bf16x8*)((const char*)(VB) + row_ * 128 + c2_);   \
        accO[fd_] = __builtin_amdgcn_mfma_f32_16x16x32_bf16(vf_, pf_,          \
                                                            accO[fd_], 0, 0, 0);\
      }                                                                        \
    }                                                                          \
    __builtin_amdgcn_s_setprio(0);                                             \
  } while (0)

  // prologue: stage Q tile + K/V tiles 0 (buf0) and 64 (buf1)
  #pragma unroll
  for (int i = 0; i < 2; ++i) {
    const int row = i * 32 + srow;
    gl_lds16(Q + qk0 + (size_t)(q0 + row) * HDIM + sc,
             (char*)lQP + i * 4096 + (w << 10));
  }
  STAGE(0, 0, lK[0], lV[0]);
  STAGE(64 * HDIM, 64, lK[1], lV[1]);
  kP += 128 * HDIM; vP += 128;
  __syncthreads();                           // drains vmcnt

  // Q fragments (stationary; own-wave rows only, P alias is same-wave safe)
  bf16x8 qf[2];
  {
    const int qrow = w * 16 + lr;
    #pragma unroll
    for (int kk = 0; kk < 2; ++kk)
      qf[kk] = *(const bf16x8*)((const char*)lQP + qrow * 128 +
                                ((kk * 64 + lh * 16) ^ ((qrow & 7) << 4)));
  }

  f32x4 accO[4];
  #pragma unroll
  for (int i = 0; i < 4; ++i) accO[i] = (f32x4){0.f, 0.f, 0.f, 0.f};
  float m = -1e30f, lsum = 0.f;

  // main loop: 15 x 128 keys; static buffer indices; each staged tile is in
  // flight exactly one compute-phase before its draining barrier.
  for (int tt = 0; tt < 15; ++tt) {
    ATILE(lK[0], lV[0]);
    __syncthreads();             // all waves done buf0; drains stage(buf1)
    STAGE(0, 0, lK[0], lV[0]);
    ATILE(lK[1], lV[1]);
    __syncthreads();             // all waves done buf1; drains stage(buf0)
    STAGE(64 * HDIM, 64, lK[1], lV[1]);
    kP += 128 * HDIM; vP += 128;
  }
  // tail: tiles 1920 (buf0) and 1984 (buf1), no further staging
  ATILE(lK[0], lV[0]);
  __syncthreads();
  ATILE(lK[1], lV[1]);

  // epilogue: reduce per-lane lsum partials across lh, then scale+store O^T
  lsum += __shfl_xor(lsum, 16, 64);
  lsum += __shfl_xor(lsum, 32, 64);
  const float rl = 1.0f / lsum;
  const int n = q0 + w * 16 + lr;
  #pragma unroll
  for (int fd = 0; fd < 4; ++fd) {
    uint2 ow;
    ow.x = cvtpk(accO[fd][0] * rl, accO[fd][1] * rl);
    ow.y = cvtpk(accO[fd][2] * rl, accO[fd][3] * rl);
    const int c = h * HDIM + fd * 16 + lh * 4;
    *(uint2*)(vals + ((size_t)b * NSEQ + n) * EMBED + c) = ow;
  }
#undef STAGE
#undef ATILE
}

// ---------------------------------------------------------------------------
extern "C" void kernel_launch(void* const* d_in, const int* in_sizes, int n_in,
                              void* d_out, int out_size, void* d_ws, size_t ws_size,
                              hipStream_t stream) {
  const float* x    = (const float*)d_in[0];
  const float* wqkv = (const float*)d_in[1];
  const float* wout = (const float*)d_in[2];
  float* y = (float*)d_out;
  char* ws = (char*)d_ws;

  // workspace layout (48 MB total)
  u16* b_wqkv = (u16*)(ws);                    // 3072*1024*2 = 6 MB
  u16* b_wout = (u16*)(ws + 6291456);          // 1024*1024*2 = 2 MB
  u16* b_xT   = (u16*)(ws + 8388608);          // 2*2048*1024*2 = 8 MB
  u16* b_Q    = (u16*)(ws + 16777216);         // [32][2048][64] = 8 MB (pre-scaled)
  u16* b_K    = (u16*)(ws + 25165824);         // 8 MB
  u16* b_Vt   = (u16*)(ws + 33554432);         // [32][64][2048] = 8 MB
  u16* b_vals = (u16*)(ws + 41943040);         // [2][2048][1024] = 8 MB

  convertw<<<4096, 256, 0, stream>>>(wqkv, wout, b_wqkv, b_wout);
  transpose_x<<<dim3(64, 32, 2), 256, 0, stream>>>(x, b_xT);
  // qkv: C[n][o] = xT[b] (2048x1024) * w_qkv^T (3072x1024)^T
  gemm_bt<0, 4><<<dim3(16, 24, 2), 256, 0, stream>>>(b_xT, b_wqkv, b_Q, b_K, b_Vt, nullptr);
  attn<<<1024, 256, 0, stream>>>(b_Q, b_K, b_Vt, b_vals);
  // out: C[o][n] = w_out (1024x1024) * vals[b]^T (2048x1024)^T  (64x128 tiles)
  gemm_bt<1, 2><<<dim3(16, 16, 2), 256, 0, stream>>>(b_wout, b_vals, nullptr, nullptr, nullptr, y);
}

// Round 9
// 189.096 us; speedup vs baseline: 1.0710x; 1.0710x over previous
//
#include <hip/hip_runtime.h>
#include <stdint.h>

typedef unsigned short u16;
typedef __attribute__((ext_vector_type(8))) short bf16x8;   // 8 bf16 in 4 VGPR
typedef __attribute__((ext_vector_type(4))) float f32x4;

#define NSEQ  2048
#define EMBED 1024
#define NHEAD 16
#define HDIM  64
// 1/sqrt(HDIM) * log2(e): S is computed in log2 domain so P = exp2(S - m)
#define QSCALE 0.1803368801111204f

// fp32 -> bf16, round-nearest-even
__device__ __forceinline__ u16 f2bf(float f) {
  uint32_t u = __builtin_bit_cast(uint32_t, f);
  u += 0x7fffu + ((u >> 16) & 1u);
  return (u16)(u >> 16);
}

// pack two fp32 -> two bf16 (RNE) in one u32 (low = a): single VALU instr
__device__ __forceinline__ uint32_t cvtpk(float a, float b) {
  uint32_t r;
  asm("v_cvt_pk_bf16_f32 %0, %1, %2" : "=v"(r) : "v"(a), "v"(b));
  return r;
}

// raw v_exp_f32 (2^x), 1 instr; arg <= 0 here, large-negative underflows to 0
__device__ __forceinline__ float ex2f(float x) {
  float r;
  asm("v_exp_f32 %0, %1" : "=v"(r) : "v"(x));
  return r;
}

// async global->LDS, 16B per lane. Dest must be wave-uniform base (+lane*16 implied).
__device__ __forceinline__ void gl_lds16(const void* g, void* l) {
  __builtin_amdgcn_global_load_lds(
      (const __attribute__((address_space(1))) void*)g,
      (__attribute__((address_space(3))) void*)l, 16, 0, 0);
}

// ---------------------------------------------------------------------------
// fp32 -> bf16 weight conversion (w_qkv: 3072x1024, w_out: 1024x1024)
// ---------------------------------------------------------------------------
struct alignas(8) us4 { u16 a, b, c, d; };

__global__ __launch_bounds__(256)
void convertw(const float* __restrict__ wq, const float* __restrict__ wo,
              u16* __restrict__ oq, u16* __restrict__ oo) {
  int idx = blockIdx.x * 256 + threadIdx.x;          // one float4 per thread
  const float* src;
  u16* dst;
  if (idx < 786432) { src = wq; dst = oq; }          // 3072*1024/4
  else { idx -= 786432; src = wo; dst = oo; }        // 1024*1024/4
  f32x4 v = ((const f32x4*)src)[idx];
  us4 r;
  r.a = f2bf(v[0]); r.b = f2bf(v[1]); r.c = f2bf(v[2]); r.d = f2bf(v[3]);
  ((us4*)dst)[idx] = r;
}

// ---------------------------------------------------------------------------
// x [B][C][N] fp32 -> xT [B][N][C] bf16   (LDS 32x33 tile transpose)
// ---------------------------------------------------------------------------
__global__ __launch_bounds__(256)
void transpose_x(const float* __restrict__ x, u16* __restrict__ xT) {
  __shared__ float tile[32][33];
  const int b = blockIdx.z;
  const int n0 = blockIdx.x * 32, c0 = blockIdx.y * 32;
  const int tx = threadIdx.x & 31, ty = threadIdx.x >> 5;   // ty 0..7
  const float* xb = x + (size_t)b * EMBED * NSEQ;
  #pragma unroll
  for (int k = 0; k < 4; ++k)
    tile[ty + k * 8][tx] = xb[(size_t)(c0 + ty + k * 8) * NSEQ + n0 + tx];
  __syncthreads();
  u16* xTb = xT + (size_t)b * NSEQ * EMBED;
  #pragma unroll
  for (int k = 0; k < 4; ++k)
    xTb[(size_t)(n0 + ty + k * 8) * EMBED + c0 + tx] = f2bf(tile[tx][ty + k * 8]);
}

// ---------------------------------------------------------------------------
// Generic C = A * B^T GEMM, A:[M][1024] bf16, B:[NC][1024] bf16, K=1024.
// Tile (MR*32) x 128, BK=64, 4 waves, 16x16x32 bf16 MFMA, fp32 acc.
// Single-buffered LDS (round-6 structure: 64KB dbuf cost a block/CU, m132),
// pointer-increment staging, PRECOMPUTED LDS base pointers (all fragment
// reads = base + compile-time const -> ds_read offset:N, no per-step VALU).
// XCD-bijective swizzle of the (m,n) tile id for B-panel L2 reuse.
// EPI 0 (MR=4, 3 blk/CU): qkv projection (scatter Q(pre-scaled), K, Vt)
// EPI 1 (MR=2): output projection (store fp32 y)
// ---------------------------------------------------------------------------
template<int EPI, int MR>
__global__ __launch_bounds__(256, (MR == 4 ? 3 : 4))
void gemm_bt(const u16* __restrict__ A, const u16* __restrict__ Bm,
             u16* __restrict__ o_q, u16* __restrict__ o_k, u16* __restrict__ o_vt,
             float* __restrict__ o_f)
{
  __shared__ u16 lA[MR * 32 * 64];
  __shared__ u16 lB[128 * 64];
  const int t  = threadIdx.x;
  const int w  = t >> 6;
  const int l  = t & 63;
  const int lr = l & 15, lh = l >> 4;
  const int wm = w >> 1, wn = w & 1;
  const int bz = blockIdx.z;
  // XCD-bijective remap: NT tiles/batch, NT%8==0
  const int NT  = (EPI == 0 ? 384 : 256);
  const int c   = blockIdx.x + 16 * blockIdx.y;
  const int swz = (c & 7) * (NT / 8) + (c >> 3);
  const int m0  = (swz & 15) * (MR * 32);
  const int n0  = (swz >> 4) * 128;

  const u16* Ab = A  + (EPI == 0 ? (size_t)bz * NSEQ * EMBED : (size_t)0);
  const u16* Bb = Bm + (EPI == 0 ? (size_t)0 : (size_t)bz * NSEQ * EMBED);

  f32x4 acc[MR][4];
  #pragma unroll
  for (int i = 0; i < MR; ++i)
    #pragma unroll
    for (int j = 0; j < 4; ++j)
      acc[i][j] = (f32x4){0.f, 0.f, 0.f, 0.f};

  const int srow = t >> 3;      // 0..31 within an issue
  const int slot = t & 7;       // 16B slot within 128B row
  const int sc   = ((slot * 16) ^ ((srow & 7) << 4)) >> 1;  // swizzled col (elems)
  const int swzr = (lr & 7) << 4;

  // precomputed LDS addresses: reads = base + const (row&7 == lr&7 for all rows)
  const char* aRd0 = (const char*)lA + (wm * (MR * 16) + lr) * 128 + ((lh * 16) ^ swzr);
  const char* aRd1 = (const char*)lA + (wm * (MR * 16) + lr) * 128 + ((64 + lh * 16) ^ swzr);
  const char* bRd0 = (const char*)lB + (wn * 64 + lr) * 128 + ((lh * 16) ^ swzr);
  const char* bRd1 = (const char*)lB + (wn * 64 + lr) * 128 + ((64 + lh * 16) ^ swzr);
  char* const aDst = (char*)lA + (w << 10);
  char* const bDst = (char*)lB + (w << 10);
  const u16* aP = Ab + (size_t)(m0 + srow) * EMBED + sc;   // +64 elems per K-step
  const u16* bP = Bb + (size_t)(n0 + srow) * EMBED + sc;

  for (int k0 = 0; k0 < 16; ++k0) {
    __syncthreads();            // previous tile fully consumed
    #pragma unroll
    for (int i = 0; i < MR; ++i)
      gl_lds16(aP + (size_t)i * 32 * EMBED, aDst + i * 4096);
    #pragma unroll
    for (int i = 0; i < 4; ++i)
      gl_lds16(bP + (size_t)i * 32 * EMBED, bDst + i * 4096);
    __syncthreads();            // staging visible (compiler drains vmcnt)
    #pragma unroll
    for (int kk = 0; kk < 2; ++kk) {
      const char* aRk = kk ? aRd1 : aRd0;
      const char* bRk = kk ? bRd1 : bRd0;
      bf16x8 af[MR], bfr[4];
      #pragma unroll
      for (int mr = 0; mr < MR; ++mr)
        af[mr] = *(const bf16x8*)(aRk + mr * 2048);
      #pragma unroll
      for (int nc = 0; nc < 4; ++nc)
        bfr[nc] = *(const bf16x8*)(bRk + nc * 2048);
      #pragma unroll
      for (int mr = 0; mr < MR; ++mr)
        #pragma unroll
        for (int nc = 0; nc < 4; ++nc)
          acc[mr][nc] = __builtin_amdgcn_mfma_f32_16x16x32_bf16(
              af[mr], bfr[nc], acc[mr][nc], 0, 0, 0);
    }
    aP += 64; bP += 64;
  }

  if constexpr (EPI == 0) {
    // rows = n (sequence), cols = o in [0,3072): o = h*192 + {q|k|v}*64 + d
    #pragma unroll
    for (int mr = 0; mr < MR; ++mr) {
      #pragma unroll
      for (int nc = 0; nc < 4; ++nc) {
        const int o  = n0 + wn * 64 + nc * 16 + lr;
        const int h  = o / 192;
        const int rr = o - h * 192;
        const size_t bh = (size_t)bz * NHEAD + h;
        #pragma unroll
        for (int r = 0; r < 4; ++r) {
          const int n = m0 + wm * (MR * 16) + mr * 16 + lh * 4 + r;
          if (rr < 64)       o_q [(bh * NSEQ + n) * HDIM + rr]         = f2bf(acc[mr][nc][r] * QSCALE);
          else if (rr < 128) o_k [(bh * NSEQ + n) * HDIM + (rr - 64)]  = f2bf(acc[mr][nc][r]);
          else               o_vt[(bh * HDIM + (rr - 128)) * NSEQ + n] = f2bf(acc[mr][nc][r]);
        }
      }
    }
  } else {
    // rows = o (out channel), cols = n; y[b][o][n] fp32, coalesced over n
    #pragma unroll
    for (int mr = 0; mr < MR; ++mr)
      #pragma unroll
      for (int nc = 0; nc < 4; ++nc)
        #pragma unroll
        for (int r = 0; r < 4; ++r) {
          const int o = m0 + wm * (MR * 16) + mr * 16 + lh * 4 + r;
          const int n = n0 + wn * 64 + nc * 16 + lr;
          o_f[((size_t)bz * EMBED + o) * NSEQ + n] = acc[mr][nc][r];
        }
  }
}

// ---------------------------------------------------------------------------
// Flash attention v6: v5 schedule (swapped-operand lane-diagonal softmax,
// static 2x unrolled K/V dbuf, raw v_exp, wave-uniform defer-max, per-lane
// lsum, XCD bh placement) + PRECOMPUTED LDS ADDRESSES: single sm[] block,
// ~10 base pointers hoisted, every ds access = base + compile-time const.
// sm layout (bytes): [0,8K) K0 | [8K,16K) K1 | [16K,24K) V0 | [24K,32K) V1
//                    | [32K,40K) Q-tile aliased by per-wave P buffers.
// LDS 40 KB -> 4 blocks/CU; grid 1024 = 4 blocks/CU exactly.
// ---------------------------------------------------------------------------
__global__ __launch_bounds__(256, 4)
void attn(const u16* __restrict__ Q, const u16* __restrict__ K,
          const u16* __restrict__ Vt, u16* __restrict__ vals)
{
  __shared__ u16 sm[5 * 64 * 64];   // 40 KB
  const int t  = threadIdx.x;
  const int w  = t >> 6, l = t & 63;
  const int lr = l & 15, lh = l >> 4;
  // XCD-aware decode: xcd = bid&7 owns bh { xcd, xcd+8, xcd+16, xcd+24 }
  const int bid = blockIdx.x;
  const int s   = bid >> 3;                  // 0..127
  const int bh  = (bid & 7) + 8 * (s >> 5);  // 4 whole heads per XCD
  const int q0  = (s & 31) * 64;
  const int b  = bh >> 4, h = bh & 15;
  const size_t qk0 = (size_t)bh * NSEQ * HDIM;
  const size_t vt0 = (size_t)bh * HDIM * NSEQ;
  const int srow = t >> 3, slot = t & 7;
  const int sc   = ((slot * 16) ^ ((srow & 7) << 4)) >> 1;  // staging col (elems)
  const int swzr = (lr & 7) << 4;

  // ---- precomputed LDS byte addresses (all later access = base + const) ----
  char* const smB  = (char*)sm;
  char* const stD  = smB + (w << 10);                          // staging dest base
  const char* kv0  = smB + lr * 128 + ((lh * 16) ^ swzr);      // K/V frag, kk=0
  const char* kv1  = smB + lr * 128 + ((64 + lh * 16) ^ swzr); // K/V frag, kk=1
  const char* kvp0 = kv0 + 32768 + (w << 11);                  // Q-frag & P-read, kk=0
  const char* kvp1 = kv1 + 32768 + (w << 11);
  char* const pwb  = smB + 32768 + (w << 11) + lr * 128;       // wave-private P row
  char* const pw_[4] = { pwb + ((0 + lh * 8) ^ swzr),  pwb + ((32 + lh * 8) ^ swzr),
                         pwb + ((64 + lh * 8) ^ swzr),  pwb + ((96 + lh * 8) ^ swzr) };

  // running global pointers (advance by 128 keys per outer iter)
  const u16* kP = K  + qk0 + (size_t)srow * HDIM + sc;
  const u16* vP = Vt + vt0 + (size_t)srow * NSEQ + sc;

// stage one 64-key K/V tile into buffer TB: key offsets KOFF (K) / VOFF (Vt)
#define STAGE(KOFF, VOFF, TB) do {                                             \
    _Pragma("unroll")                                                          \
    for (int i_ = 0; i_ < 2; ++i_) {                                           \
      gl_lds16(kP + (KOFF) + (size_t)i_ * 32 * HDIM,                           \
               stD + (TB) * 8192 + i_ * 4096);                                 \
      gl_lds16(vP + (VOFF) + (size_t)i_ * 32 * NSEQ,                           \
               stD + 16384 + (TB) * 8192 + i_ * 4096);                         \
    }                                                                          \
  } while (0)

// process one 64-key tile from buffer TB (S^T -> softmax -> O^T += PV)
#define ATILE(TB) do {                                                         \
    f32x4 accS[4];                                                             \
    _Pragma("unroll")                                                          \
    for (int f_ = 0; f_ < 4; ++f_) accS[f_] = (f32x4){0.f, 0.f, 0.f, 0.f};     \
    __builtin_amdgcn_s_setprio(1);                                             \
    _Pragma("unroll")                                                          \
    for (int kk_ = 0; kk_ < 2; ++kk_) {                                        \
      const char* kvk_ = kk_ ? kv1 : kv0;                                      \
      _Pragma("unroll")                                                        \
      for (int f_ = 0; f_ < 4; ++f_) {                                         \
        bf16x8 kf_ = *(const bf16x8*)(kvk_ + (TB) * 8192 + f_ * 2048);         \
        accS[f_] = __builtin_amdgcn_mfma_f32_16x16x32_bf16(kf_, qf[kk_],       \
                                                           accS[f_], 0, 0, 0);\
      }                                                                        \
    }                                                                          \
    __builtin_amdgcn_s_setprio(0);                                             \
    float fm0_ = fmaxf(fmaxf(accS[0][0], accS[0][1]), fmaxf(accS[0][2], accS[0][3])); \
    float fm1_ = fmaxf(fmaxf(accS[1][0], accS[1][1]), fmaxf(accS[1][2], accS[1][3])); \
    float fm2_ = fmaxf(fmaxf(accS[2][0], accS[2][1]), fmaxf(accS[2][2], accS[2][3])); \
    float fm3_ = fmaxf(fmaxf(accS[3][0], accS[3][1]), fmaxf(accS[3][2], accS[3][3])); \
    float tm_ = fmaxf(fmaxf(fm0_, fm1_), fmaxf(fm2_, fm3_));                   \
    tm_ = fmaxf(tm_, __shfl_xor(tm_, 16, 64));                                 \
    tm_ = fmaxf(tm_, __shfl_xor(tm_, 32, 64));                                 \
    if (__any(tm_ - m > 8.f)) {   /* wave-uniform defer-max */                 \
      const float nm_ = fmaxf(m, tm_);                                         \
      const float al_ = ex2f(m - nm_);   /* lanes w/o growth: ex2(0)=1 */      \
      lsum *= al_;                                                             \
      _Pragma("unroll")                                                        \
      for (int fd_ = 0; fd_ < 4; ++fd_)                                        \
        _Pragma("unroll")                                                      \
        for (int r_ = 0; r_ < 4; ++r_) accO[fd_][r_] *= al_;                   \
      m = nm_;                                                                 \
    }                                                                          \
    _Pragma("unroll")                                                          \
    for (int f_ = 0; f_ < 4; ++f_) {                                           \
      const float e0_ = ex2f(accS[f_][0] - m);                                 \
      const float e1_ = ex2f(accS[f_][1] - m);                                 \
      const float e2_ = ex2f(accS[f_][2] - m);                                 \
      const float e3_ = ex2f(accS[f_][3] - m);                                 \
      lsum += (e0_ + e1_) + (e2_ + e3_);   /* per-lane partial */              \
      uint2 pw_v;                                                              \
      pw_v.x = cvtpk(e0_, e1_);                                                \
      pw_v.y = cvtpk(e2_, e3_);                                                \
      *(uint2*)(pw_[f_]) = pw_v;                                               \
    }                                                                          \
    __builtin_amdgcn_s_setprio(1);                                             \
    _Pragma("unroll")                                                          \
    for (int kk_ = 0; kk_ < 2; ++kk_) {                                        \
      const char* kvk_ = kk_ ? kv1 : kv0;                                      \
      bf16x8 pf_ = *(const bf16x8*)(kk_ ? kvp1 : kvp0);                        \
      _Pragma("unroll")                                                        \
      for (int fd_ = 0; fd_ < 4; ++fd_) {                                      \
        bf16x8 vf_ = *(const bf16x8*)(kvk_ + 16384 + (TB) * 8192 + fd_ * 2048);\
        accO[fd_] = __builtin_amdgcn_mfma_f32_16x16x32_bf16(vf_, pf_,          \
                                                            accO[fd_], 0, 0, 0);\
      }                                                                        \
    }                                                                          \
    __builtin_amdgcn_s_setprio(0);                                             \
  } while (0)

  // prologue: stage Q tile (into [32K,40K)) + K/V tiles 0 (buf0) and 64 (buf1)
  #pragma unroll
  for (int i = 0; i < 2; ++i)
    gl_lds16(Q + qk0 + (size_t)(q0 + i * 32 + srow) * HDIM + sc,
             stD + 32768 + i * 4096);
  STAGE(0, 0, 0);
  STAGE(64 * HDIM, 64, 1);
  kP += 128 * HDIM; vP += 128;
  __syncthreads();                           // drains vmcnt

  // Q fragments (stationary; reads own-wave rows only -> P alias is safe)
  bf16x8 qf[2];
  qf[0] = *(const bf16x8*)kvp0;
  qf[1] = *(const bf16x8*)kvp1;

  f32x4 accO[4];
  #pragma unroll
  for (int i = 0; i < 4; ++i) accO[i] = (f32x4){0.f, 0.f, 0.f, 0.f};
  float m = -1e30f, lsum = 0.f;

  // main loop: 15 x 128 keys; static buffer indices; each staged tile is in
  // flight exactly one compute-phase before its draining barrier.
  for (int tt = 0; tt < 15; ++tt) {
    ATILE(0);
    __syncthreads();             // all waves done buf0; drains stage(buf1)
    STAGE(0, 0, 0);
    ATILE(1);
    __syncthreads();             // all waves done buf1; drains stage(buf0)
    STAGE(64 * HDIM, 64, 1);
    kP += 128 * HDIM; vP += 128;
  }
  // tail: tiles 1920 (buf0) and 1984 (buf1), no further staging
  ATILE(0);
  __syncthreads();
  ATILE(1);

  // epilogue: reduce per-lane lsum partials across lh, then scale+store O^T
  lsum += __shfl_xor(lsum, 16, 64);
  lsum += __shfl_xor(lsum, 32, 64);
  const float rl = 1.0f / lsum;
  const int n = q0 + w * 16 + lr;
  #pragma unroll
  for (int fd = 0; fd < 4; ++fd) {
    uint2 ow;
    ow.x = cvtpk(accO[fd][0] * rl, accO[fd][1] * rl);
    ow.y = cvtpk(accO[fd][2] * rl, accO[fd][3] * rl);
    const int c = h * HDIM + fd * 16 + lh * 4;
    *(uint2*)(vals + ((size_t)b * NSEQ + n) * EMBED + c) = ow;
  }
#undef STAGE
#undef ATILE
}

// ---------------------------------------------------------------------------
extern "C" void kernel_launch(void* const* d_in, const int* in_sizes, int n_in,
                              void* d_out, int out_size, void* d_ws, size_t ws_size,
                              hipStream_t stream) {
  const float* x    = (const float*)d_in[0];
  const float* wqkv = (const float*)d_in[1];
  const float* wout = (const float*)d_in[2];
  float* y = (float*)d_out;
  char* ws = (char*)d_ws;

  // workspace layout (48 MB total)
  u16* b_wqkv = (u16*)(ws);                    // 3072*1024*2 = 6 MB
  u16* b_wout = (u16*)(ws + 6291456);          // 1024*1024*2 = 2 MB
  u16* b_xT   = (u16*)(ws + 8388608);          // 2*2048*1024*2 = 8 MB
  u16* b_Q    = (u16*)(ws + 16777216);         // [32][2048][64] = 8 MB (pre-scaled)
  u16* b_K    = (u16*)(ws + 25165824);         // 8 MB
  u16* b_Vt   = (u16*)(ws + 33554432);         // [32][64][2048] = 8 MB
  u16* b_vals = (u16*)(ws + 41943040);         // [2][2048][1024] = 8 MB

  convertw<<<4096, 256, 0, stream>>>(wqkv, wout, b_wqkv, b_wout);
  transpose_x<<<dim3(64, 32, 2), 256, 0, stream>>>(x, b_xT);
  // qkv: C[n][o] = xT[b] (2048x1024) * w_qkv^T (3072x1024)^T
  gemm_bt<0, 4><<<dim3(16, 24, 2), 256, 0, stream>>>(b_xT, b_wqkv, b_Q, b_K, b_Vt, nullptr);
  attn<<<1024, 256, 0, stream>>>(b_Q, b_K, b_Vt, b_vals);
  // out: C[o][n] = w_out (1024x1024) * vals[b]^T (2048x1024)^T  (64x128 tiles)
  gemm_bt<1, 2><<<dim3(16, 16, 2), 256, 0, stream>>>(b_wout, b_vals, nullptr, nullptr, nullptr, y);
}